// Round 2
// baseline (173.889 us; speedup 1.0000x reference)
//
#include <hip/hip_runtime.h>
#include <hip/hip_bf16.h>
#include <math.h>

#define S 256
#define D 128
#define H 4
#define HD 32
#define NT (S * S)

constexpr float EPS = 1e-5f;
constexpr float EXPC = 0.17677669529663687f * 1.44269504088896f;  // scale*log2(e)

typedef short bf16x8 __attribute__((ext_vector_type(8)));
typedef float floatx4 __attribute__((ext_vector_type(4)));

union BfBits { __hip_bfloat16 b; unsigned short u; };
__device__ inline unsigned short f2bf_bits(float f) {
  BfBits t;
  t.b = __float2bfloat16(f);
  return t.u;
}
__device__ inline short f2bf_s(float f) { return (short)f2bf_bits(f); }
__device__ inline float bfbits2f(unsigned short u) {
  union { float f; unsigned int i; } t;
  t.i = ((unsigned int)u) << 16;
  return t.f;
}
// split x into bf16 hi + bf16 lo with x ~= hi + lo (error <= 2^-18 relative)
__device__ inline void split_bf(float x, unsigned short& hi, unsigned short& lo) {
  hi = f2bf_bits(x);
  lo = f2bf_bits(x - bfbits2f(hi));
}

// ---------------------------------------------------------------------------
// K0: split the four 128x128 fp32 weights into bf16 hi/lo pairs, original
// [d][c] layout (== MFMA A-operand row layout). Order: q, k, v, o.
// ---------------------------------------------------------------------------
__global__ __launch_bounds__(256) void wsplit_kernel(
    const float* __restrict__ wq, const float* __restrict__ wk,
    const float* __restrict__ wv, const float* __restrict__ wo,
    unsigned short* __restrict__ whi, unsigned short* __restrict__ wlo) {
  int idx = blockIdx.x * 256 + threadIdx.x;  // 0..16383
  const float* srcs[4] = {wq, wk, wv, wo};
#pragma unroll
  for (int m = 0; m < 4; m++) {
    unsigned short hi, lo;
    split_bf(srcs[m][idx], hi, lo);
    whi[m * 16384 + idx] = hi;
    wlo[m * 16384 + idx] = lo;
  }
}

// ---------------------------------------------------------------------------
// K1 R9: fused LayerNorm + QKV projection, LOOP-INVERTED.
// R8 post-mortem: occupancy 37->69% made it SLOWER (58.8 vs 49.7 us) —
// MfmaUtil fell, bank conflicts byte-identical (786432 = +4cy per
// ds_read_b128 in BOTH pad and XOR layouts: c16/c16+8 lanes alias whenever
// row-stride == 0 mod 32 words; column-XOR can't fix it). Kernel is
// per-wave-efficiency starved, not TLP starved.
// New structure: wave owns 32 TOKENS resident in registers (bh[2][4], read
// from LDS exactly once — LDS reads drop 196K->16K, conflicts moot) and
// sweeps ALL 24 m-tiles (3 mats x 8), streaming weight fragments from L2:
// 8 independent 16B loads -> 16 MFMAs per m-tile, #pragma unroll 2 for
// prefetch depth. 512 blocks x 128 tokens; no __syncthreads (each wave
// reads only its own LDS rows). (256,2): est ~124 VGPR; if FETCH balloons
// vs 17 MB, it spilled.
// ---------------------------------------------------------------------------
#define XS(row, col) ((col) ^ (((row) & 7) << 3))
__global__ __launch_bounds__(256, 2) void qkv_ln_mfma_kernel(
    const float* __restrict__ pair, const float* __restrict__ ln_w,
    const unsigned short* __restrict__ Whi,
    const unsigned short* __restrict__ Wlo, unsigned short* __restrict__ Qb,
    unsigned short* __restrict__ Kb, unsigned short* __restrict__ Vt) {
  __shared__ unsigned short xhi[128][D];  // 32 KB, per-wave private rows
  const int t0 = blockIdx.x * 128;
  const int wave = threadIdx.x >> 6;
  const int lane = threadIdx.x & 63;
  const int c16 = lane & 15;
  const int quad = lane >> 4;

  // ---- LayerNorm: wave's 32 tokens, 4 concurrent per group (quad=token) ----
  {
    float4 w0 = *(const float4*)(ln_w + c16 * 8);
    float4 w1 = *(const float4*)(ln_w + c16 * 8 + 4);
#pragma unroll
    for (int g = 0; g < 8; g++) {
      const int tok = wave * 32 + g * 4 + quad;
      const float* src = pair + (size_t)(t0 + tok) * D + c16 * 8;
      float4 x0 = *(const float4*)(src);
      float4 x1 = *(const float4*)(src + 4);
      float s = (x0.x + x0.y) + (x0.z + x0.w) + (x1.x + x1.y) + (x1.z + x1.w);
      s += __shfl_xor(s, 1);
      s += __shfl_xor(s, 2);
      s += __shfl_xor(s, 4);
      s += __shfl_xor(s, 8);
      const float mu = s * (1.0f / D);
      float a[8];
      a[0] = x0.x - mu; a[1] = x0.y - mu; a[2] = x0.z - mu; a[3] = x0.w - mu;
      a[4] = x1.x - mu; a[5] = x1.y - mu; a[6] = x1.z - mu; a[7] = x1.w - mu;
      float vs = 0.f;
#pragma unroll
      for (int r = 0; r < 8; r++) vs = fmaf(a[r], a[r], vs);
      vs += __shfl_xor(vs, 1);
      vs += __shfl_xor(vs, 2);
      vs += __shfl_xor(vs, 4);
      vs += __shfl_xor(vs, 8);
      const float rinv = rsqrtf(vs * (1.0f / D) + EPS);
      const float w[8] = {w0.x, w0.y, w0.z, w0.w, w1.x, w1.y, w1.z, w1.w};
      unsigned int u[4];
#pragma unroll
      for (int r = 0; r < 4; r++) {
        unsigned int h0 = f2bf_bits(a[2 * r] * rinv * w[2 * r]);
        unsigned int h1 = f2bf_bits(a[2 * r + 1] * rinv * w[2 * r + 1]);
        u[r] = h0 | (h1 << 16);
      }
      uint4 st = {u[0], u[1], u[2], u[3]};
      *(uint4*)&xhi[tok][XS(tok, c16 * 8)] = st;
    }
  }
  // no __syncthreads: each wave reads back only rows it wrote itself;
  // compiler inserts the lgkmcnt wait for the same-wave write->read dep.

  // ---- read the wave's 32 tokens into MFMA B-fragments ONCE ----
  bf16x8 bh[2][4];
#pragma unroll
  for (int nt = 0; nt < 2; nt++)
#pragma unroll
    for (int ks = 0; ks < 4; ks++) {
      const int row = wave * 32 + nt * 16 + c16;
      bh[nt][ks] = *(const bf16x8*)&xhi[row][XS(row, ks * 32 + quad * 8)];
    }

  const int i_ = t0 >> 8;      // pair row index (128 | 256 => constant per block)
  const int jbase = t0 & 255;  // token offset within the pair row

  // ---- sweep all m-tiles: 3 mats x 8 tiles, weights streamed from L2 ----
  for (int mat = 0; mat < 3; mat++) {
    const unsigned short* whi_m = Whi + mat * 16384;
    const unsigned short* wlo_m = Wlo + mat * 16384;
#pragma unroll 2
    for (int mt = 0; mt < 8; mt++) {
      const int m0 = mt * 16;
      floatx4 acc[2];
      acc[0] = (floatx4){0.f, 0.f, 0.f, 0.f};
      acc[1] = (floatx4){0.f, 0.f, 0.f, 0.f};
#pragma unroll
      for (int ks = 0; ks < 4; ks++) {
        bf16x8 ah = *(const bf16x8*)(whi_m + (m0 + c16) * D + ks * 32 + quad * 8);
        bf16x8 al = *(const bf16x8*)(wlo_m + (m0 + c16) * D + ks * 32 + quad * 8);
        acc[0] = __builtin_amdgcn_mfma_f32_16x16x32_bf16(ah, bh[0][ks], acc[0], 0, 0, 0);
        acc[0] = __builtin_amdgcn_mfma_f32_16x16x32_bf16(al, bh[0][ks], acc[0], 0, 0, 0);
        acc[1] = __builtin_amdgcn_mfma_f32_16x16x32_bf16(ah, bh[1][ks], acc[1], 0, 0, 0);
        acc[1] = __builtin_amdgcn_mfma_f32_16x16x32_bf16(al, bh[1][ks], acc[1], 0, 0, 0);
      }

      // ---- epilogue for this m-tile ----
      const int d0 = m0 + quad * 4;  // 4 consecutive out dims
      const int h = d0 >> 5;
      const int hd = d0 & 31;
#pragma unroll
      for (int nt = 0; nt < 2; nt++) {
        const int j = jbase + wave * 32 + nt * 16 + c16;
        floatx4 v4 = acc[nt];
        if (mat < 2) {
          ushort4 pk;
          pk.x = f2bf_bits(v4[0]);
          pk.y = f2bf_bits(v4[1]);
          pk.z = f2bf_bits(v4[2]);
          pk.w = f2bf_bits(v4[3]);
          unsigned short* dst = (mat == 0) ? Qb : Kb;
          size_t off = (((size_t)h * S + i_) * S + j) * HD + hd;
          *(ushort4*)(dst + off) = pk;
        } else {
#pragma unroll
          for (int r = 0; r < 4; r++) {
            size_t off = (((size_t)h * S + i_) * HD + (hd + r)) * S + j;
            Vt[off] = f2bf_bits(v4[r]);
          }
        }
      }
    }
  }
}

// ---------------------------------------------------------------------------
// K2: FUSED flash attention + output projection (R7 regrid — kept).
// Block = (pair-row i, quarter p): 256 threads = 4 waves = 4 heads; each wave
// runs attention for its head over the quarter's 64 queries, deposits O as
// packed (hi | lo<<16) bf16 into LDS, then all 4 waves project those 64
// tokens (wave owns 2 outdim tiles). 1024 blocks, 34 KB LDS -> 4 blocks/CU.
// ---------------------------------------------------------------------------
#define OLD 133  // LDS row stride (words) for O buffer
__global__ __launch_bounds__(256, 4) void attn_oproj_kernel(
    const unsigned short* __restrict__ Qb, const unsigned short* __restrict__ Kb,
    const unsigned short* __restrict__ Vt, const unsigned short* __restrict__ Whi,
    const unsigned short* __restrict__ Wlo, float* __restrict__ out) {
  __shared__ unsigned int Ols[64][OLD];  // 34 KB
  const int i = blockIdx.x;
  const int p = blockIdx.y;  // quarter: tokens p*64 .. p*64+63
  const int h = threadIdx.x >> 6;  // wave = head
  const int lane = threadIdx.x & 63;
  const int c = lane & 15;
  const int quad = lane >> 4;
  const int q0 = p * 64;

  const unsigned short* Qbase = Qb + (((size_t)h * S + i) * S) * HD;
  const unsigned short* Kbase = Kb + (((size_t)h * S + i) * S) * HD;
  const unsigned short* Vbase = Vt + (((size_t)h * S + i) * HD) * S;

  // ---- Phase 1: attention for this head's 64 queries (4 q-tiles) ----
  bf16x8 qf[4];
#pragma unroll
  for (int qt = 0; qt < 4; qt++)
    qf[qt] = *(const bf16x8*)(Qbase + (size_t)(q0 + qt * 16 + c) * HD + quad * 8);

  floatx4 acc[2][4];
#pragma unroll
  for (int dt = 0; dt < 2; dt++)
#pragma unroll
    for (int qt = 0; qt < 4; qt++) acc[dt][qt] = (floatx4){0.f, 0.f, 0.f, 0.f};
  float lsum[4] = {0.f, 0.f, 0.f, 0.f};

  const int permc = ((c >> 2) * 8) + (c & 3);

  for (int jb = 0; jb < S; jb += 32) {
    bf16x8 kf0 = *(const bf16x8*)(Kbase + (size_t)(jb + permc + 0) * HD + quad * 8);
    bf16x8 kf1 = *(const bf16x8*)(Kbase + (size_t)(jb + permc + 4) * HD + quad * 8);
    bf16x8 vf0 = *(const bf16x8*)(Vbase + (size_t)(0 * 16 + c) * S + jb + quad * 8);
    bf16x8 vf1 = *(const bf16x8*)(Vbase + (size_t)(1 * 16 + c) * S + jb + quad * 8);

#pragma unroll
    for (int qt = 0; qt < 4; qt++) {
      floatx4 s0 = __builtin_amdgcn_mfma_f32_16x16x32_bf16(
          kf0, qf[qt], (floatx4){0.f, 0.f, 0.f, 0.f}, 0, 0, 0);
      floatx4 s1 = __builtin_amdgcn_mfma_f32_16x16x32_bf16(
          kf1, qf[qt], (floatx4){0.f, 0.f, 0.f, 0.f}, 0, 0, 0);
      float pr[8];
#pragma unroll
      for (int r = 0; r < 4; r++) pr[r] = exp2f(s0[r] * EXPC);
#pragma unroll
      for (int r = 0; r < 4; r++) pr[4 + r] = exp2f(s1[r] * EXPC);
      float ls = 0.f;
#pragma unroll
      for (int r = 0; r < 8; r++) ls += pr[r];
      lsum[qt] += ls;
      bf16x8 pf;
#pragma unroll
      for (int r = 0; r < 8; r++) pf[r] = f2bf_s(pr[r]);
      acc[0][qt] = __builtin_amdgcn_mfma_f32_16x16x32_bf16(vf0, pf, acc[0][qt], 0, 0, 0);
      acc[1][qt] = __builtin_amdgcn_mfma_f32_16x16x32_bf16(vf1, pf, acc[1][qt], 0, 0, 0);
    }
  }

#pragma unroll
  for (int qt = 0; qt < 4; qt++) {
    float l = lsum[qt];
    l += __shfl_xor(l, 16);
    l += __shfl_xor(l, 32);
    lsum[qt] = 1.0f / l;
  }

  // ---- deposit O (head's 32 dims) for the 64 tokens as packed hi|lo<<16 ----
#pragma unroll
  for (int t = 0; t < 4; t++) {
    const float inv = lsum[t];
#pragma unroll
    for (int dt = 0; dt < 2; dt++) {
      floatx4 v4 = acc[dt][t];
      uint4 st;
      unsigned short hh, ll;
      split_bf(v4[0] * inv, hh, ll); st.x = (unsigned)hh | ((unsigned)ll << 16);
      split_bf(v4[1] * inv, hh, ll); st.y = (unsigned)hh | ((unsigned)ll << 16);
      split_bf(v4[2] * inv, hh, ll); st.z = (unsigned)hh | ((unsigned)ll << 16);
      split_bf(v4[3] * inv, hh, ll); st.w = (unsigned)hh | ((unsigned)ll << 16);
      *(uint4*)&Ols[t * 16 + c][h * 32 + dt * 16 + quad * 4] = st;
    }
  }

  // ---- load wo fragments: wave owns outdim tiles wave*32, wave*32+16 ----
  bf16x8 woh[2][4], wol[2][4];
#pragma unroll
  for (int mi = 0; mi < 2; mi++)
#pragma unroll
    for (int ks = 0; ks < 4; ks++) {
      const int m0 = h * 32 + mi * 16;
      woh[mi][ks] = *(const bf16x8*)(Whi + 3 * 16384 + (m0 + c) * D + ks * 32 + quad * 8);
      wol[mi][ks] = *(const bf16x8*)(Wlo + 3 * 16384 + (m0 + c) * D + ks * 32 + quad * 8);
    }

  __syncthreads();

  // ---- Phase 2: project the 64 tokens: out = O @ wo^T ----
  floatx4 oacc[2][4];
#pragma unroll
  for (int mi = 0; mi < 2; mi++)
#pragma unroll
    for (int nt = 0; nt < 4; nt++) oacc[mi][nt] = (floatx4){0.f, 0.f, 0.f, 0.f};

#pragma unroll
  for (int ks = 0; ks < 4; ks++) {
#pragma unroll
    for (int nt = 0; nt < 4; nt++) {
      const unsigned int* src = &Ols[nt * 16 + c][ks * 32 + quad * 8];
      uint4 u0 = *(const uint4*)(src);
      uint4 u1 = *(const uint4*)(src + 4);
      unsigned int bhw[4], blw[4];
      bhw[0] = (u0.x & 0xFFFFu) | (u0.y << 16);
      blw[0] = (u0.x >> 16) | (u0.y & 0xFFFF0000u);
      bhw[1] = (u0.z & 0xFFFFu) | (u0.w << 16);
      blw[1] = (u0.z >> 16) | (u0.w & 0xFFFF0000u);
      bhw[2] = (u1.x & 0xFFFFu) | (u1.y << 16);
      blw[2] = (u1.x >> 16) | (u1.y & 0xFFFF0000u);
      bhw[3] = (u1.z & 0xFFFFu) | (u1.w << 16);
      blw[3] = (u1.z >> 16) | (u1.w & 0xFFFF0000u);
      bf16x8 bh = *(bf16x8*)bhw;
      bf16x8 bl = *(bf16x8*)blw;
#pragma unroll
      for (int mi = 0; mi < 2; mi++) {
        oacc[mi][nt] = __builtin_amdgcn_mfma_f32_16x16x32_bf16(woh[mi][ks], bh, oacc[mi][nt], 0, 0, 0);
        oacc[mi][nt] = __builtin_amdgcn_mfma_f32_16x16x32_bf16(woh[mi][ks], bl, oacc[mi][nt], 0, 0, 0);
        oacc[mi][nt] = __builtin_amdgcn_mfma_f32_16x16x32_bf16(wol[mi][ks], bh, oacc[mi][nt], 0, 0, 0);
      }
    }
  }

#pragma unroll
  for (int mi = 0; mi < 2; mi++) {
    const int m0 = h * 32 + mi * 16;
#pragma unroll
    for (int nt = 0; nt < 4; nt++) {
      float4 st;
      st.x = oacc[mi][nt][0];
      st.y = oacc[mi][nt][1];
      st.z = oacc[mi][nt][2];
      st.w = oacc[mi][nt][3];
      *(float4*)(out + ((size_t)i * S + q0 + nt * 16 + c) * D + m0 + quad * 4) = st;
    }
  }
}

// ---------------------------------------------------------------------------
extern "C" void kernel_launch(void* const* d_in, const int* in_sizes, int n_in,
                              void* d_out, int out_size, void* d_ws,
                              size_t ws_size, hipStream_t stream) {
  const float* pair = (const float*)d_in[0];
  const float* ln_w = (const float*)d_in[1];
  const float* wq = (const float*)d_in[2];
  const float* wk = (const float*)d_in[3];
  const float* wv = (const float*)d_in[4];
  const float* wo = (const float*)d_in[5];
  float* out = (float*)d_out;

  const size_t NE = (size_t)NT * D;  // 8388608
  unsigned short* base = (unsigned short*)d_ws;
  unsigned short* Qb = base;
  unsigned short* Kb = base + NE;
  unsigned short* Vt = base + 2 * NE;
  unsigned short* Whi = base + 3 * NE;
  unsigned short* Wlo = base + 3 * NE + 4 * 16384;

  wsplit_kernel<<<64, 256, 0, stream>>>(wq, wk, wv, wo, Whi, Wlo);
  qkv_ln_mfma_kernel<<<NT / 128, 256, 0, stream>>>(pair, ln_w, Whi, Wlo, Qb, Kb,
                                                   Vt);
  attn_oproj_kernel<<<dim3(S, 4), 256, 0, stream>>>(Qb, Kb, Vt, Whi, Wlo, out);
}

// Round 3
// 159.477 us; speedup vs baseline: 1.0904x; 1.0904x over previous
//
#include <hip/hip_runtime.h>
#include <hip/hip_bf16.h>
#include <math.h>

#define S 256
#define D 128
#define H 4
#define HD 32
#define NT (S * S)

constexpr float EPS = 1e-5f;
constexpr float EXPC = 0.17677669529663687f * 1.44269504088896f;  // scale*log2(e)

typedef short bf16x8 __attribute__((ext_vector_type(8)));
typedef float floatx4 __attribute__((ext_vector_type(4)));

union BfBits { __hip_bfloat16 b; unsigned short u; };
__device__ inline unsigned short f2bf_bits(float f) {
  BfBits t;
  t.b = __float2bfloat16(f);
  return t.u;
}
__device__ inline short f2bf_s(float f) { return (short)f2bf_bits(f); }
__device__ inline float bfbits2f(unsigned short u) {
  union { float f; unsigned int i; } t;
  t.i = ((unsigned int)u) << 16;
  return t.f;
}
// split x into bf16 hi + bf16 lo with x ~= hi + lo (error <= 2^-18 relative)
__device__ inline void split_bf(float x, unsigned short& hi, unsigned short& lo) {
  hi = f2bf_bits(x);
  lo = f2bf_bits(x - bfbits2f(hi));
}
__device__ inline unsigned int pk2(float a, float b) {
  return (unsigned int)f2bf_bits(a) | ((unsigned int)f2bf_bits(b) << 16);
}

// ---------------------------------------------------------------------------
// K0: split the four 128x128 fp32 weights into bf16 hi/lo pairs, original
// [d][c] layout (== MFMA A-operand row layout). Order: q, k, v, o.
// ---------------------------------------------------------------------------
__global__ __launch_bounds__(256) void wsplit_kernel(
    const float* __restrict__ wq, const float* __restrict__ wk,
    const float* __restrict__ wv, const float* __restrict__ wo,
    unsigned short* __restrict__ whi, unsigned short* __restrict__ wlo) {
  int idx = blockIdx.x * 256 + threadIdx.x;  // 0..16383
  const float* srcs[4] = {wq, wk, wv, wo};
#pragma unroll
  for (int m = 0; m < 4; m++) {
    unsigned short hi, lo;
    split_bf(srcs[m][idx], hi, lo);
    whi[m * 16384 + idx] = hi;
    wlo[m * 16384 + idx] = lo;
  }
}

// ---------------------------------------------------------------------------
// R10 MEGA-FUSION: one kernel per pair-row i. R0-R2 post-mortem: three
// structurally different LN+QKV kernels all pinned at hbm_bytes/~1.3TB/s
// with every pipe idle -> the lever is TRAFFIC, not tiling. This kernel
// never materializes Q/K/V in global memory:
//   P1 LN(256 tok) -> xn LDS (64KB, XS row-XOR swizzle)
//   P2 Q = xn@wq^T -> per-wave register fragments via cross-quad shfl
//      (wave (h,half) owns head h, queries half*128..+127; 8 qtiles)
//   P3 per 64-token j-tile: produce K,V tiles into swizzled LDS
//      (Kt 16KB [h][hdchunk][j][8hd]; Vt 16KB [h][hd][jchunk^hd&7][8j]),
//      then flash-accumulate attention from LDS (no running max, as before)
//   P4 lsum reduce; O deposited hi|lo-packed into Ost (32KB = Kt/Vt pool
//      reused, chunk^tok&15 swizzle) per 64-token chunk; all 8 waves
//      project chunk with wo (3-MFMA hi/lo scheme); fp32 out store.
// All rounding points identical to the 3-kernel pipeline -> same absmax.
// Global traffic: pair 32MB in + out 32MB out (+256KB weights), vs ~115MB.
// LDS swizzles verified <=2-way except Q-frag path (shfl, no LDS).
// ---------------------------------------------------------------------------
#define XS(row, col) ((col) ^ (((row) & 7) << 3))

__global__ __launch_bounds__(512, 2) void fused_tri_kernel(
    const float* __restrict__ pair, const float* __restrict__ ln_w,
    const unsigned short* __restrict__ Whi,
    const unsigned short* __restrict__ Wlo, float* __restrict__ out) {
  __shared__ unsigned short xn[256][D];   // 64KB
  __shared__ unsigned int kvpool[8192];   // 32KB: Kt(16K)|Vt(16K), reused as Ost
  unsigned short* Kt = (unsigned short*)kvpool;         // [h][c2][j64][8hd]
  unsigned short* Vt = (unsigned short*)kvpool + 8192;  // [h][hd32][jc^ (hd&7)][8j]
  unsigned int* Ost = kvpool;                           // [tok64][128 d] u32 packed

  const int i = blockIdx.x;
  const int w = (int)(threadIdx.x >> 6);
  const int lane = (int)(threadIdx.x & 63);
  const int c16 = lane & 15;
  const int quad = lane >> 4;
  const int h = w >> 1;
  const int half = w & 1;

  // ---- P1: LayerNorm, 32 tokens/wave (4 parallel x 8 groups) ----
  {
    float4 w0 = *(const float4*)(ln_w + c16 * 8);
    float4 w1 = *(const float4*)(ln_w + c16 * 8 + 4);
#pragma unroll
    for (int g = 0; g < 8; g++) {
      const int tok = w * 32 + g * 4 + quad;
      const float* src = pair + ((size_t)i * S + tok) * D + c16 * 8;
      float4 x0 = *(const float4*)(src);
      float4 x1 = *(const float4*)(src + 4);
      float s = (x0.x + x0.y) + (x0.z + x0.w) + (x1.x + x1.y) + (x1.z + x1.w);
      s += __shfl_xor(s, 1);
      s += __shfl_xor(s, 2);
      s += __shfl_xor(s, 4);
      s += __shfl_xor(s, 8);
      const float mu = s * (1.0f / D);
      float a[8];
      a[0] = x0.x - mu; a[1] = x0.y - mu; a[2] = x0.z - mu; a[3] = x0.w - mu;
      a[4] = x1.x - mu; a[5] = x1.y - mu; a[6] = x1.z - mu; a[7] = x1.w - mu;
      float vs = 0.f;
#pragma unroll
      for (int r = 0; r < 8; r++) vs = fmaf(a[r], a[r], vs);
      vs += __shfl_xor(vs, 1);
      vs += __shfl_xor(vs, 2);
      vs += __shfl_xor(vs, 4);
      vs += __shfl_xor(vs, 8);
      const float rinv = rsqrtf(vs * (1.0f / D) + EPS);
      const float wv8[8] = {w0.x, w0.y, w0.z, w0.w, w1.x, w1.y, w1.z, w1.w};
      unsigned int u[4];
#pragma unroll
      for (int r = 0; r < 4; r++) {
        unsigned int h0 = f2bf_bits(a[2 * r] * rinv * wv8[2 * r]);
        unsigned int h1 = f2bf_bits(a[2 * r + 1] * rinv * wv8[2 * r + 1]);
        u[r] = h0 | (h1 << 16);
      }
      uint4 st = {u[0], u[1], u[2], u[3]};
      *(uint4*)&xn[tok][XS(tok, c16 * 8)] = st;
    }
  }
  __syncthreads();

  // ---- P2: Q projection -> register fragments (per-wave 128 queries) ----
  bf16x8 qf[8];
  {
#pragma unroll
    for (int r = 0; r < 2; r++) {
      floatx4 acc[2][4];
#pragma unroll
      for (int mi = 0; mi < 2; mi++)
#pragma unroll
        for (int nt = 0; nt < 4; nt++) acc[mi][nt] = (floatx4){0.f, 0.f, 0.f, 0.f};
#pragma unroll
      for (int ks = 0; ks < 4; ks++) {
        bf16x8 bh[4];
#pragma unroll
        for (int nt = 0; nt < 4; nt++) {
          const int row = half * 128 + r * 64 + nt * 16 + c16;
          bh[nt] = *(const bf16x8*)&xn[row][XS(row, ks * 32 + quad * 8)];
        }
#pragma unroll
        for (int mi = 0; mi < 2; mi++) {
          const int arow = h * 32 + mi * 16 + c16;
          bf16x8 ah = *(const bf16x8*)(Whi + arow * D + ks * 32 + quad * 8);
          bf16x8 al = *(const bf16x8*)(Wlo + arow * D + ks * 32 + quad * 8);
#pragma unroll
          for (int nt = 0; nt < 4; nt++) {
            acc[mi][nt] = __builtin_amdgcn_mfma_f32_16x16x32_bf16(ah, bh[nt], acc[mi][nt], 0, 0, 0);
            acc[mi][nt] = __builtin_amdgcn_mfma_f32_16x16x32_bf16(al, bh[nt], acc[mi][nt], 0, 0, 0);
          }
        }
      }
      // redistribute across quads: proj layout (4 consecutive d per lane)
      // -> attention B-fragment (8 consecutive hd per lane). token col (c16)
      // is already aligned; only quads exchange.
      const int srcL = c16 + (quad & 1) * 32;
      const int srcH = srcL + 16;
      const bool hi2 = quad >= 2;
#pragma unroll
      for (int nt = 0; nt < 4; nt++) {
        int pa = (int)pk2(acc[0][nt][0], acc[0][nt][1]);
        int pb = (int)pk2(acc[0][nt][2], acc[0][nt][3]);
        int pc = (int)pk2(acc[1][nt][0], acc[1][nt][1]);
        int pd = (int)pk2(acc[1][nt][2], acc[1][nt][3]);
        int aL = __shfl(pa, srcL), cL = __shfl(pc, srcL);
        int bL = __shfl(pb, srcL), dL = __shfl(pd, srcL);
        int aH = __shfl(pa, srcH), cH = __shfl(pc, srcH);
        int bH = __shfl(pb, srcH), dH = __shfl(pd, srcH);
        union { unsigned int u[4]; bf16x8 v; } qq;
        qq.u[0] = (unsigned int)(hi2 ? cL : aL);
        qq.u[1] = (unsigned int)(hi2 ? dL : bL);
        qq.u[2] = (unsigned int)(hi2 ? cH : aH);
        qq.u[3] = (unsigned int)(hi2 ? dH : bH);
        qf[r * 4 + nt] = qq.v;
      }
    }
  }

  // ---- P3: j-tile loop: produce K/V tile in LDS, consume attention ----
  floatx4 att[2][8];
#pragma unroll
  for (int dt = 0; dt < 2; dt++)
#pragma unroll
    for (int qt = 0; qt < 8; qt++) att[dt][qt] = (floatx4){0.f, 0.f, 0.f, 0.f};
  float lsum[8] = {0.f, 0.f, 0.f, 0.f, 0.f, 0.f, 0.f, 0.f};
  const int permc = ((c16 >> 2) * 8) + (c16 & 3);

  for (int jt = 0; jt < 4; jt++) {
    __syncthreads();
    // -- produce: wave w computes K,V for head h, hd half*16..+15, 64 tokens
    {
      const int hb = half * 16;
      const unsigned short* wkh = Whi + 16384;
      const unsigned short* wkl = Wlo + 16384;
      const unsigned short* wvh = Whi + 32768;
      const unsigned short* wvl = Wlo + 32768;
      floatx4 ak[4], av[4];
#pragma unroll
      for (int nt = 0; nt < 4; nt++) {
        ak[nt] = (floatx4){0.f, 0.f, 0.f, 0.f};
        av[nt] = (floatx4){0.f, 0.f, 0.f, 0.f};
      }
#pragma unroll
      for (int ks = 0; ks < 4; ks++) {
        bf16x8 bh[4];
#pragma unroll
        for (int nt = 0; nt < 4; nt++) {
          const int row = jt * 64 + nt * 16 + c16;
          bh[nt] = *(const bf16x8*)&xn[row][XS(row, ks * 32 + quad * 8)];
        }
        const int arow = h * 32 + hb + c16;
        bf16x8 kh = *(const bf16x8*)(wkh + arow * D + ks * 32 + quad * 8);
        bf16x8 kl = *(const bf16x8*)(wkl + arow * D + ks * 32 + quad * 8);
        bf16x8 vh = *(const bf16x8*)(wvh + arow * D + ks * 32 + quad * 8);
        bf16x8 vl = *(const bf16x8*)(wvl + arow * D + ks * 32 + quad * 8);
#pragma unroll
        for (int nt = 0; nt < 4; nt++) {
          ak[nt] = __builtin_amdgcn_mfma_f32_16x16x32_bf16(kh, bh[nt], ak[nt], 0, 0, 0);
          ak[nt] = __builtin_amdgcn_mfma_f32_16x16x32_bf16(kl, bh[nt], ak[nt], 0, 0, 0);
          av[nt] = __builtin_amdgcn_mfma_f32_16x16x32_bf16(vh, bh[nt], av[nt], 0, 0, 0);
          av[nt] = __builtin_amdgcn_mfma_f32_16x16x32_bf16(vl, bh[nt], av[nt], 0, 0, 0);
        }
      }
      const int c2 = half * 2 + (quad >> 1);
#pragma unroll
      for (int nt = 0; nt < 4; nt++) {
        const int jl = nt * 16 + c16;
        ushort4 pkk;
        pkk.x = f2bf_bits(ak[nt][0]);
        pkk.y = f2bf_bits(ak[nt][1]);
        pkk.z = f2bf_bits(ak[nt][2]);
        pkk.w = f2bf_bits(ak[nt][3]);
        *(ushort4*)(Kt + h * 2048 + c2 * 512 + jl * 8 + (quad & 1) * 4) = pkk;
#pragma unroll
        for (int r2 = 0; r2 < 4; r2++) {
          const int hd = hb + quad * 4 + r2;
          Vt[h * 2048 + hd * 64 + (((jl >> 3) ^ (hd & 7)) << 3) + (jl & 7)] =
              f2bf_bits(av[nt][r2]);
        }
      }
    }
    __syncthreads();
    // -- consume: attention accumulate for this wave's 128 queries
#pragma unroll
    for (int jb = 0; jb < 2; jb++) {
      const int jbl = jb * 32;
      bf16x8 kf0 = *(const bf16x8*)(Kt + h * 2048 + quad * 512 + (jbl + permc) * 8);
      bf16x8 kf1 = *(const bf16x8*)(Kt + h * 2048 + quad * 512 + (jbl + permc + 4) * 8);
      const int ch = (jbl >> 3) + quad;
      bf16x8 vf0 = *(const bf16x8*)(Vt + h * 2048 + c16 * 64 + ((ch ^ (c16 & 7)) << 3));
      bf16x8 vf1 = *(const bf16x8*)(Vt + h * 2048 + (16 + c16) * 64 + ((ch ^ (c16 & 7)) << 3));
#pragma unroll
      for (int qt = 0; qt < 8; qt++) {
        floatx4 s0 = __builtin_amdgcn_mfma_f32_16x16x32_bf16(
            kf0, qf[qt], (floatx4){0.f, 0.f, 0.f, 0.f}, 0, 0, 0);
        floatx4 s1 = __builtin_amdgcn_mfma_f32_16x16x32_bf16(
            kf1, qf[qt], (floatx4){0.f, 0.f, 0.f, 0.f}, 0, 0, 0);
        float pr[8];
#pragma unroll
        for (int r = 0; r < 4; r++) pr[r] = exp2f(s0[r] * EXPC);
#pragma unroll
        for (int r = 0; r < 4; r++) pr[4 + r] = exp2f(s1[r] * EXPC);
        float ls = 0.f;
#pragma unroll
        for (int r = 0; r < 8; r++) ls += pr[r];
        lsum[qt] += ls;
        bf16x8 pf;
#pragma unroll
        for (int r = 0; r < 8; r++) pf[r] = f2bf_s(pr[r]);
        att[0][qt] = __builtin_amdgcn_mfma_f32_16x16x32_bf16(vf0, pf, att[0][qt], 0, 0, 0);
        att[1][qt] = __builtin_amdgcn_mfma_f32_16x16x32_bf16(vf1, pf, att[1][qt], 0, 0, 0);
      }
    }
  }

  // ---- P4: normalize factors, then per-64-token-chunk oproj ----
#pragma unroll
  for (int qt = 0; qt < 8; qt++) {
    float l = lsum[qt];
    l += __shfl_xor(l, 16);
    l += __shfl_xor(l, 32);
    lsum[qt] = 1.0f / l;
  }

  bf16x8 woh[4], wol[4];
#pragma unroll
  for (int ks = 0; ks < 4; ks++) {
    woh[ks] = *(const bf16x8*)(Whi + 3 * 16384 + (w * 16 + c16) * D + ks * 32 + quad * 8);
    wol[ks] = *(const bf16x8*)(Wlo + 3 * 16384 + (w * 16 + c16) * D + ks * 32 + quad * 8);
  }

#pragma unroll
  for (int cc = 0; cc < 4; cc++) {
    __syncthreads();
    if ((cc >> 1) == half) {  // this wave owns the chunk's queries for head h
#pragma unroll
      for (int t = 0; t < 4; t++) {
        const int qg = (cc & 1) * 4 + t;
        const float inv = lsum[qg];
        const int tok = t * 16 + c16;
#pragma unroll
        for (int dt = 0; dt < 2; dt++) {
          floatx4 v4 = att[dt][qg];
          unsigned int u[4];
          unsigned short hh, ll;
          split_bf(v4[0] * inv, hh, ll); u[0] = (unsigned)hh | ((unsigned)ll << 16);
          split_bf(v4[1] * inv, hh, ll); u[1] = (unsigned)hh | ((unsigned)ll << 16);
          split_bf(v4[2] * inv, hh, ll); u[2] = (unsigned)hh | ((unsigned)ll << 16);
          split_bf(v4[3] * inv, hh, ll); u[3] = (unsigned)hh | ((unsigned)ll << 16);
          const int chunk = h * 8 + dt * 4 + quad;
          uint4 st = {u[0], u[1], u[2], u[3]};
          *(uint4*)(Ost + tok * 128 + ((chunk ^ c16) << 2)) = st;
        }
      }
    }
    __syncthreads();
    // all 8 waves project: wave w -> outdims w*16..+15
    floatx4 oacc[4];
#pragma unroll
    for (int nt = 0; nt < 4; nt++) oacc[nt] = (floatx4){0.f, 0.f, 0.f, 0.f};
#pragma unroll
    for (int ks = 0; ks < 4; ks++) {
#pragma unroll
      for (int nt = 0; nt < 4; nt++) {
        const int tok = nt * 16 + c16;
        const int ch0 = ks * 8 + quad * 2;
        uint4 u0 = *(const uint4*)(Ost + tok * 128 + ((ch0 ^ c16) << 2));
        uint4 u1 = *(const uint4*)(Ost + tok * 128 + (((ch0 + 1) ^ c16) << 2));
        unsigned int bhw[4], blw[4];
        bhw[0] = (u0.x & 0xFFFFu) | (u0.y << 16);
        blw[0] = (u0.x >> 16) | (u0.y & 0xFFFF0000u);
        bhw[1] = (u0.z & 0xFFFFu) | (u0.w << 16);
        blw[1] = (u0.z >> 16) | (u0.w & 0xFFFF0000u);
        bhw[2] = (u1.x & 0xFFFFu) | (u1.y << 16);
        blw[2] = (u1.x >> 16) | (u1.y & 0xFFFF0000u);
        bhw[3] = (u1.z & 0xFFFFu) | (u1.w << 16);
        blw[3] = (u1.z >> 16) | (u1.w & 0xFFFF0000u);
        bf16x8 bh = *(bf16x8*)bhw;
        bf16x8 bl = *(bf16x8*)blw;
        oacc[nt] = __builtin_amdgcn_mfma_f32_16x16x32_bf16(woh[ks], bh, oacc[nt], 0, 0, 0);
        oacc[nt] = __builtin_amdgcn_mfma_f32_16x16x32_bf16(woh[ks], bl, oacc[nt], 0, 0, 0);
        oacc[nt] = __builtin_amdgcn_mfma_f32_16x16x32_bf16(wol[ks], bh, oacc[nt], 0, 0, 0);
      }
    }
#pragma unroll
    for (int nt = 0; nt < 4; nt++) {
      float4 st4;
      st4.x = oacc[nt][0];
      st4.y = oacc[nt][1];
      st4.z = oacc[nt][2];
      st4.w = oacc[nt][3];
      *(float4*)(out + ((size_t)i * S + cc * 64 + nt * 16 + c16) * D + w * 16 + quad * 4) = st4;
    }
  }
}

// ---------------------------------------------------------------------------
extern "C" void kernel_launch(void* const* d_in, const int* in_sizes, int n_in,
                              void* d_out, int out_size, void* d_ws,
                              size_t ws_size, hipStream_t stream) {
  const float* pair = (const float*)d_in[0];
  const float* ln_w = (const float*)d_in[1];
  const float* wq = (const float*)d_in[2];
  const float* wk = (const float*)d_in[3];
  const float* wv = (const float*)d_in[4];
  const float* wo = (const float*)d_in[5];
  float* out = (float*)d_out;

  unsigned short* Whi = (unsigned short*)d_ws;
  unsigned short* Wlo = Whi + 4 * 16384;

  wsplit_kernel<<<64, 256, 0, stream>>>(wq, wk, wv, wo, Whi, Wlo);
  fused_tri_kernel<<<S, 512, 0, stream>>>(pair, ln_w, Whi, Wlo, out);
}